// Round 11
// baseline (280.337 us; speedup 1.0000x reference)
//
#include <hip/hip_runtime.h>

#define DEVINL __device__ __forceinline__

typedef __bf16 bf16x8 __attribute__((ext_vector_type(8)));
typedef float  f32x4  __attribute__((ext_vector_type(4)));

// ---------------- constants / ws layout ----------------
// B=256, C=1024, H=64, E=64, K=2, MI=128, tokens T = 262144
static constexpr size_t kAdjOff  = 0;                 // 2*1024 f32 (8 KB)
static constexpr size_t kBiasOff = 8192;              // 64*3*4*64*4 f32 = 786432 B
static constexpr size_t kFragOff = 8192 + 786432;     // 112 frags * 1024 B = 114688 B

// Weight fragments (units: one frag = 64 lanes * 16 B).
// Built by prep_wfrag as B-frags of W: lane l slot j = W[32ks+pi(q,j)][16nt+(l&15)].
// ROUND 19 reinterpretation: the same data IS the A-frag of W^T (m-tile = nt) --
// no prep change needed.
static constexpr int FB_Wn1h0 = 0,  FB_Wn1h1 = 8,  FB_Wn2_0 = 16, FB_Wn2_1 = 24;
static constexpr int FB_Ws1h  = 32, FB_Ws2   = 40, FB_We    = 48, FB_Wa    = 56;
static constexpr int FB_Wih   = 64, FB_Whh   = 88;

// ---------------- helpers ----------------
DEVINL unsigned short bf16r(float f) {           // RTNE float->bf16
  unsigned u = __builtin_bit_cast(unsigned, f);
  unsigned r = ((u >> 16) & 1u) + 0x7FFFu;
  return (unsigned short)((u + r) >> 16);
}
DEVINL float sigmoidf_(float x) { return __builtin_amdgcn_rcpf(1.f + __expf(-x)); }
DEVINL float tanhf_(float x)    { return 1.f - 2.f * __builtin_amdgcn_rcpf(1.f + __expf(2.f * x)); }

// HW packed f32->bf16 (RNE)
DEVINL unsigned pkbf(float a, float b) {
  unsigned d;
  asm("v_cvt_pk_bf16_f32 %0, %1, %2" : "=v"(d) : "v"(a), "v"(b));
  return d;
}

DEVINL f32x4 mfma16(bf16x8 a, bf16x8 b, f32x4 c) {
  return __builtin_amdgcn_mfma_f32_16x16x32_bf16(a, b, c, 0, 0, 0);
}

DEVINL unsigned clip2_(unsigned x) {   // clamp two packed bf16 to [-5,5]; exact repack
  float lo = __builtin_bit_cast(float, x << 16);
  float hi = __builtin_bit_cast(float, x & 0xFFFF0000u);
  lo = fminf(fmaxf(lo, -5.f), 5.f);
  hi = fminf(fmaxf(hi, -5.f), 5.f);
  return (__builtin_bit_cast(unsigned, lo) >> 16) | (__builtin_bit_cast(unsigned, hi) & 0xFFFF0000u);
}
DEVINL bf16x8 clip5(bf16x8 a) {
  uint4 u = __builtin_bit_cast(uint4, a);
  u.x = clip2_(u.x); u.y = clip2_(u.y); u.z = clip2_(u.z); u.w = clip2_(u.w);
  return __builtin_bit_cast(bf16x8, u);
}

// D-regs -> B-frag (the swapped-operand register handoff).
// B-frag slot j (phys k = ks*32 + pi(q,j)): j<4 <- m-tile 2ks reg r=j (h=32ks+q*4+j);
// j>=4 <- m-tile 2ks+1 reg r=j-4 (h=32ks+16+q*4+(j-4)). Pure VALU: 4 cvt_pk.
DEVINL bf16x8 d2b(f32x4 lo, f32x4 hi) {
  uint4 t;
  t.x = pkbf(lo[0], lo[1]);
  t.y = pkbf(lo[2], lo[3]);
  t.z = pkbf(hi[0], hi[1]);
  t.w = pkbf(hi[2], hi[3]);
  return __builtin_bit_cast(bf16x8, t);
}

// ---------------- prep 1: adjacency vector (SPARSE: a0 has ~5 nonzeros) ----------------
__global__ void prep_adj_kernel(const int* __restrict__ qt, const float* __restrict__ onehot,
                                const float* __restrict__ graphs, float* __restrict__ adjw) {
  __shared__ float a0v[1024];
  __shared__ int   aidx[1024];
  __shared__ int   s_nnz;
  __shared__ float s_den;
  const int tid = threadIdx.x;
  const int k = blockIdx.x >> 2, chunk = blockIdx.x & 3;   // 8 blocks: 2k x 4 chunks of 256 d
  if (tid == 0) { s_nnz = 0; s_den = 0.f; }
  __syncthreads();
  const int q0 = qt[0];
  float lsum = 0.f;
#pragma unroll
  for (int i = 0; i < 4; i++) {
    int c = tid * 4 + i;
    float v = onehot[(size_t)q0 * 1024 + c];
    lsum += v;
    if (v != 0.f) { int p = atomicAdd(&s_nnz, 1); aidx[p] = c; a0v[p] = v; }
  }
#pragma unroll
  for (int off = 32; off >= 1; off >>= 1) lsum += __shfl_xor(lsum, off, 64);
  if ((tid & 63) == 0) atomicAdd(&s_den, lsum);
  __syncthreads();
  const float denom = fmaxf(s_den, 1.f);
  const int nnz = s_nnz;
  const int d = chunk * 256 + tid;
  const float* G = graphs + (size_t)k * 1048576 + d;
  float sum = 0.f;
  for (int j = 0; j < nnz; j++) sum += a0v[j] * G[(size_t)aidx[j] * 1024];
  adjw[k * 1024 + d] = fminf(fmaxf(sum / denom, -5.f), 5.f);
}

// ---------------- prep 2: per-c bias tables (kc folded into layer-1 bias) ----------------
// ROUND 19 layout (transposed D): element (h, t) of block c16:
// biasTab[(((c16*3+tab)*4 + (h>>4))*64 + ((h&15)>>2)*16 + (c&15))*4 + (h&3)]
__global__ void prep_bias_kernel(const float* __restrict__ kc, const float* __restrict__ Wn1,
                                 const float* __restrict__ bn1, const float* __restrict__ Ws1,
                                 const float* __restrict__ bs1, float* __restrict__ biasTab) {
  int gid = blockIdx.x * 256 + threadIdx.x;   // 196608 total
  int j = gid & 63;                           // h (output feature)
  int c = (gid >> 6) & 1023;                  // token column
  int tab = gid >> 16;                        // 0,1 neigh-k; 2 self
  const float* kcr = kc + (size_t)c * 64;
  float s;
  if (tab < 2) {
    s = bn1[tab * 64 + j];
    const float* W = Wn1 + ((size_t)tab * 256 + 192) * 64 + j;   // kc rows of neigh net
#pragma unroll 4
    for (int e = 0; e < 64; e++) s += fminf(fmaxf(kcr[e], -5.f), 5.f) * W[(size_t)e * 64];
  } else {
    s = bs1[j];
    const float* W = Ws1 + (size_t)64 * 64 + j;                  // kc rows of self net (unclipped)
#pragma unroll 4
    for (int e = 0; e < 64; e++) s += kcr[e] * W[(size_t)e * 64];
  }
  int c16 = c >> 4, m = j >> 4, qh = (j & 15) >> 2, r = j & 3, tc = c & 15;
  biasTab[(size_t)((((c16 * 3 + tab) * 4 + m) * 64 + qh * 16 + tc)) * 4 + r] = s;
}

// ---------------- prep 3: weights -> bf16 fragments (pi-permuted; UNCHANGED) ------------
// frag(FB + ks*4 + nt): lane l slot j = W[32ks + pi(q,j)][16nt + (l&15)], q=l>>4,
// pi(q,j) = (j<4) ? q*4+j : 16+q*4+(j-4). Used in r19 as A-frag of W^T (m-tile = nt).
__global__ void prep_wfrag_kernel(const float* __restrict__ Wn1, const float* __restrict__ Wn2,
                                  const float* __restrict__ Ws1, const float* __restrict__ Ws2,
                                  const float* __restrict__ We,  const float* __restrict__ Wa,
                                  const float* __restrict__ Wih, const float* __restrict__ Whh,
                                  uint4* __restrict__ wfrag) {
  const int bid = blockIdx.x, lane = threadIdx.x;   // 112 blocks x 64 threads
  int mat, ks, nt;
  if (bid < 64) { mat = bid >> 3; ks = (bid >> 2) & 1; nt = bid & 3; }
  else { int f2 = bid - 64; mat = 8 + f2 / 24; int f = f2 % 24; ks = f / 12; nt = f % 12; }
  const float* base = Wn1; int stride = 64;
  switch (mat) {
    case 0: base = Wn1 + (size_t)128 * 64; break;          // Wn1 k0, ht rows 128..191
    case 1: base = Wn1 + (size_t)(256 + 128) * 64; break;  // Wn1 k1
    case 2: base = Wn2; break;
    case 3: base = Wn2 + (size_t)64 * 64; break;
    case 4: base = Ws1; break;                             // rows 0..63 (ht part)
    case 5: base = Ws2; break;
    case 6: base = We; break;
    case 7: base = Wa; break;
    case 8: base = Wih; stride = 192; break;
    case 9: base = Whh; stride = 192; break;
  }
  const int qq = lane >> 4, col = nt * 16 + (lane & 15);
  union { unsigned short u[8]; uint4 v; } tmp;
#pragma unroll
  for (int jj = 0; jj < 8; jj++) {
    int k = ks * 32 + ((jj < 4) ? (qq * 4 + jj) : (16 + qq * 4 + (jj - 4)));
    tmp.u[jj] = bf16r(base[(size_t)k * stride + col]);
  }
  wfrag[(size_t)bid * 64 + lane] = tmp.v;
}

// ---------------- main fused kernel ----------------
// ROUND 19: SWAPPED-OPERAND MFMA pipeline -- every layer computes out^T = W^T * act^T
// (A = weight frag, B = activation frag). The D layout (col=lane&15=token,
// row=q*4+r=feature) IS the pi-permuted B-frag of the next layer: d2b() converts in
// registers (4 cvt_pk). Consequences vs r17:
//  * ZERO LDS, zero __syncthreads, zero volatile asm, zero tr-reads -- the ~220 DS
//    ops and five lgkmcnt(0) chain-serialization points per wave are gone;
//  * ht loaded directly as B-frags (4x16B coalesced per lane per stream);
//  * per-token params (mask/adj/g) are per-lane SCALARS (token = lane&15);
//  * biases are f32x4 vector loads (feature = 16m+q*4+r);
//  * output write coalesced (lanes 0..15 write 16 consecutive floats).
// 2 blocks/CU via (256,2); stream-split GRU keeps arch peak ~116 < 128.
__global__ __launch_bounds__(256, 2) void gkt_main_kernel(
    const int* __restrict__ qt, const float* __restrict__ onehot, const float* __restrict__ ht,
    const float* __restrict__ nw, const float* __restrict__ bn2, const float* __restrict__ be,
    const float* __restrict__ ba, const float* __restrict__ bih, const float* __restrict__ bhh,
    const float* __restrict__ Wp, const float* __restrict__ bp, const float* __restrict__ eaw,
    const float* __restrict__ bs2, const float* __restrict__ adjw, const float* __restrict__ biasTab,
    const bf16x8* __restrict__ wfrag, float* __restrict__ out) {
  const int tid = threadIdx.x;
  const int wv = tid >> 6, lane = tid & 63;
  const int q = lane >> 4, tl = lane & 15;
  const int t0 = (blockIdx.x * 4 + wv) * 32;
  const int b = t0 >> 10, c0 = t0 & 1023, c16 = c0 >> 4;
  const int cA = c0 + tl, cB = cA + 16;
  const size_t gtA = (size_t)t0 + tl, gtB = gtA + 16;

  // ---- per-token scalars (token = lane&15; broadcast across q-groups) ----
  const int qb = qt[b];
  const float mkA = onehot[(size_t)qb * 1024 + cA];
  const float mkB = onehot[(size_t)qb * 1024 + cB];
  const float adA0 = adjw[cA], adA1 = adjw[1024 + cA];
  const float adB0 = adjw[cB], adB1 = adjw[1024 + cB];
  const float gA = eaw[cA], gB = eaw[cB];
  const float wmix = fminf(fmaxf(nw[0], 0.1f), 0.9f);

  // ---- ht as B-frags: frag ks, slot j = ht[c][32ks + pi(q,j)] ----
  const float4* ht4 = (const float4*)ht;
  auto loadHtB = [&](size_t gt, int ks) -> bf16x8 {
    float4 v0 = ht4[gt * 16 + 8 * ks + q];        // feats 32ks+q*4 .. +3   (j=0..3)
    float4 v1 = ht4[gt * 16 + 8 * ks + 4 + q];    // feats 32ks+16+q*4 .. +3 (j=4..7)
    uint4 t;
    t.x = pkbf(v0.x, v0.y); t.y = pkbf(v0.z, v0.w);
    t.z = pkbf(v1.x, v1.y); t.w = pkbf(v1.z, v1.w);
    return __builtin_bit_cast(bf16x8, t);
  };
  bf16x8 xrA[2] = {loadHtB(gtA, 0), loadHtB(gtA, 1)};
  bf16x8 xrB[2] = {loadHtB(gtB, 0), loadHtB(gtB, 1)};

  auto ldW = [&](int frag) -> bf16x8 { return wfrag[frag * 64 + lane]; };  // A-operand
  const f32x4* bt4 = (const f32x4*)biasTab;

  f32x4 nfA[4], nfB[4];   // nf[m][r]: feature h = 16m + q*4 + r, token = lane&15

  // ---- weight prefetch (one phase ahead; source-order, r15-proven) ----
  bf16x8 fX[8], fY[8];
#pragma unroll
  for (int i = 0; i < 8; i++) fX[i] = ldW(FB_Wn1h0 + i);   // fX[ks*4+m]

  // ---- neighbor path ----
#pragma unroll
  for (int k2 = 0; k2 < 2; k2++) {
#pragma unroll
    for (int i = 0; i < 8; i++) fY[i] = ldW((k2 ? FB_Wn2_1 : FB_Wn2_0) + i);
    bf16x8 xcA[2] = {clip5(xrA[0]), clip5(xrA[1])};
    bf16x8 xcB[2] = {clip5(xrB[0]), clip5(xrB[1])};
    f32x4 acA[4], acB[4];
#pragma unroll
    for (int m = 0; m < 4; m++) {
      acA[m] = bt4[(((c16    ) * 3 + k2) * 4 + m) * 64 + lane];
      acB[m] = bt4[(((c16 + 1) * 3 + k2) * 4 + m) * 64 + lane];
    }
#pragma unroll
    for (int ks = 0; ks < 2; ks++)
#pragma unroll
      for (int m = 0; m < 4; m++) {
        bf16x8 w = fX[ks * 4 + m];
        acA[m] = mfma16(w, xcA[ks], acA[m]);
        acB[m] = mfma16(w, xcB[ks], acB[m]);
      }
    // prefetch next phase's layer-1 frags
#pragma unroll
    for (int i = 0; i < 8; i++) fX[i] = ldW((k2 ? FB_Ws1h : FB_Wn1h1) + i);
    // relu -> register handoff to layer 2
    f32x4 r1A[4], r1B[4];
#pragma unroll
    for (int m = 0; m < 4; m++)
#pragma unroll
      for (int r = 0; r < 4; r++) {
        r1A[m][r] = fmaxf(acA[m][r], 0.f);
        r1B[m][r] = fmaxf(acB[m][r], 0.f);
      }
    bf16x8 pA0 = d2b(r1A[0], r1A[1]), pA1 = d2b(r1A[2], r1A[3]);
    bf16x8 pB0 = d2b(r1B[0], r1B[1]), pB1 = d2b(r1B[2], r1B[3]);
    f32x4 c2A[4], c2B[4];
#pragma unroll
    for (int m = 0; m < 4; m++) {
      f32x4 bz = *(const f32x4*)&bn2[k2 * 64 + m * 16 + q * 4];
      c2A[m] = bz; c2B[m] = bz;
    }
#pragma unroll
    for (int m = 0; m < 4; m++) {
      c2A[m] = mfma16(fY[m],     pA0, c2A[m]);
      c2A[m] = mfma16(fY[4 + m], pA1, c2A[m]);
      c2B[m] = mfma16(fY[m],     pB0, c2B[m]);
      c2B[m] = mfma16(fY[4 + m], pB1, c2B[m]);
    }
#pragma unroll
    for (int m = 0; m < 4; m++)
#pragma unroll
      for (int r = 0; r < 4; r++) {
        float nbA = fminf(fmaxf(c2A[m][r], 0.f), 5.f);
        float nbB = fminf(fmaxf(c2B[m][r], 0.f), 5.f);
        float vA = (k2 ? adA1 : adA0) * nbA;
        float vB = (k2 ? adB1 : adB0) * nbB;
        if (k2 == 0) {
          nfA[m][r] = wmix * fminf(fmaxf(vA, -5.f), 5.f);
          nfB[m][r] = wmix * fminf(fmaxf(vB, -5.f), 5.f);
        } else {
          nfA[m][r] = fminf(fmaxf(nfA[m][r] + (1.f - wmix) * vA, -5.f), 5.f);
          nfB[m][r] = fminf(fmaxf(nfB[m][r] + (1.f - wmix) * vB, -5.f), 5.f);
        }
      }
  }

  // ---- self path (fX holds Ws1h) ----
  bool anySelf = __any((mkA > 0.5f) || (mkB > 0.5f));
  if (anySelf) {
#pragma unroll
    for (int i = 0; i < 8; i++) fY[i] = ldW(FB_Ws2 + i);
    f32x4 acA[4], acB[4];
#pragma unroll
    for (int m = 0; m < 4; m++) {
      acA[m] = bt4[(((c16    ) * 3 + 2) * 4 + m) * 64 + lane];
      acB[m] = bt4[(((c16 + 1) * 3 + 2) * 4 + m) * 64 + lane];
    }
#pragma unroll
    for (int ks = 0; ks < 2; ks++)
#pragma unroll
      for (int m = 0; m < 4; m++) {
        bf16x8 w = fX[ks * 4 + m];
        acA[m] = mfma16(w, xrA[ks], acA[m]);    // raw (unclipped) ht
        acB[m] = mfma16(w, xrB[ks], acB[m]);
      }
    f32x4 r1A[4], r1B[4];
#pragma unroll
    for (int m = 0; m < 4; m++)
#pragma unroll
      for (int r = 0; r < 4; r++) {
        r1A[m][r] = fmaxf(acA[m][r], 0.f);
        r1B[m][r] = fmaxf(acB[m][r], 0.f);
      }
    bf16x8 pA0 = d2b(r1A[0], r1A[1]), pA1 = d2b(r1A[2], r1A[3]);
    bf16x8 pB0 = d2b(r1B[0], r1B[1]), pB1 = d2b(r1B[2], r1B[3]);
    f32x4 c2A[4], c2B[4];
#pragma unroll
    for (int m = 0; m < 4; m++) {
      f32x4 bz = *(const f32x4*)&bs2[m * 16 + q * 4];
      c2A[m] = bz; c2B[m] = bz;
    }
#pragma unroll
    for (int m = 0; m < 4; m++) {
      c2A[m] = mfma16(fY[m],     pA0, c2A[m]);
      c2A[m] = mfma16(fY[4 + m], pA1, c2A[m]);
      c2B[m] = mfma16(fY[m],     pB0, c2B[m]);
      c2B[m] = mfma16(fY[4 + m], pB1, c2B[m]);
    }
#pragma unroll
    for (int m = 0; m < 4; m++)
#pragma unroll
      for (int r = 0; r < 4; r++) {
        float sfA = fminf(fmaxf(c2A[m][r], 0.f), 10.f);
        float sfB = fminf(fmaxf(c2B[m][r], 0.f), 10.f);
        nfA[m][r] = (mkA > 0.5f) ? sfA : nfA[m][r];
        nfB[m][r] = (mkB > 0.5f) ? sfB : nfB[m][r];
      }
  }

  // ---- res = m - g*sigmoid(m@We+be)*m + g*tanh(m@Wa+ba) ----
#pragma unroll
  for (int i = 0; i < 8; i++) fX[i] = ldW(FB_We + i);
  bf16x8 mA0 = d2b(nfA[0], nfA[1]), mA1 = d2b(nfA[2], nfA[3]);
  bf16x8 mB0 = d2b(nfB[0], nfB[1]), mB1 = d2b(nfB[2], nfB[3]);
  {
#pragma unroll
    for (int i = 0; i < 8; i++) fY[i] = ldW(FB_Wa + i);
    f32x4 eA[4], eB[4];
#pragma unroll
    for (int m = 0; m < 4; m++) {
      f32x4 bz = *(const f32x4*)&be[m * 16 + q * 4];
      eA[m] = bz; eB[m] = bz;
    }
#pragma unroll
    for (int m = 0; m < 4; m++) {
      eA[m] = mfma16(fX[m],     mA0, eA[m]);
      eA[m] = mfma16(fX[4 + m], mA1, eA[m]);
      eB[m] = mfma16(fX[m],     mB0, eB[m]);
      eB[m] = mfma16(fX[4 + m], mB1, eB[m]);
    }
#pragma unroll
    for (int m = 0; m < 4; m++)
#pragma unroll
      for (int r = 0; r < 4; r++) {
        float mAv = nfA[m][r], mBv = nfB[m][r];
        nfA[m][r] = mAv - gA * sigmoidf_(eA[m][r]) * mAv;
        nfB[m][r] = mBv - gB * sigmoidf_(eB[m][r]) * mBv;
      }
    f32x4 aA[4], aB[4];
#pragma unroll
    for (int m = 0; m < 4; m++) {
      f32x4 bz = *(const f32x4*)&ba[m * 16 + q * 4];
      aA[m] = bz; aB[m] = bz;
    }
#pragma unroll
    for (int m = 0; m < 4; m++) {
      aA[m] = mfma16(fY[m],     mA0, aA[m]);
      aA[m] = mfma16(fY[4 + m], mA1, aA[m]);
      aB[m] = mfma16(fY[m],     mB0, aB[m]);
      aB[m] = mfma16(fY[4 + m], mB1, aB[m]);
    }
#pragma unroll
    for (int m = 0; m < 4; m++)
#pragma unroll
      for (int r = 0; r < 4; r++) {
        nfA[m][r] += gA * tanhf_(aA[m][r]);
        nfB[m][r] += gB * tanhf_(aB[m][r]);
      }
  }

  // ---- GRU gates + output (stream-split; all handoffs in registers) ----
  const float bpv = bp[0];
  auto gruStream = [&](const f32x4* nf, const bf16x8* xr, size_t gt, int tbase) {
    bf16x8 rf0 = d2b(nf[0], nf[1]), rf1 = d2b(nf[2], nf[3]);   // res B-frags
    // epilogue prefetch: fp32 ht + per-feature vectors (short live range)
    f32x4 htv[4], wpv[4], brz[4], bzz[4], bnn[4], bhn[4];
#pragma unroll
    for (int m = 0; m < 4; m++) {
      htv[m] = *(const f32x4*)&ht[gt * 64 + m * 16 + q * 4];
      wpv[m] = *(const f32x4*)&Wp[m * 16 + q * 4];
      f32x4 bi0 = *(const f32x4*)&bih[m * 16 + q * 4];
      f32x4 bh0 = *(const f32x4*)&bhh[m * 16 + q * 4];
      f32x4 bi1 = *(const f32x4*)&bih[64 + m * 16 + q * 4];
      f32x4 bh1 = *(const f32x4*)&bhh[64 + m * 16 + q * 4];
#pragma unroll
      for (int r = 0; r < 4; r++) {
        brz[m][r] = bi0[r] + bh0[r];
        bzz[m][r] = bi1[r] + bh1[r];
      }
      bnn[m] = *(const f32x4*)&bih[128 + m * 16 + q * 4];
      bhn[m] = *(const f32x4*)&bhh[128 + m * 16 + q * 4];
    }
    f32x4 gR[4], gZ[4], gN[4], gH[4];
#pragma unroll
    for (int m = 0; m < 4; m++) { gR[m] = brz[m]; gZ[m] = bzz[m]; gN[m] = bnn[m]; gH[m] = bhn[m]; }
#pragma unroll
    for (int ks = 0; ks < 2; ks++) {
      bf16x8 rfk = ks ? rf1 : rf0;
      bf16x8 xrk = xr[ks];
#pragma unroll
      for (int m = 0; m < 4; m++) {
        gR[m] = mfma16(ldW(FB_Wih + ks * 12 + m),     rfk, gR[m]);
        gR[m] = mfma16(ldW(FB_Whh + ks * 12 + m),     xrk, gR[m]);
        gZ[m] = mfma16(ldW(FB_Wih + ks * 12 + 4 + m), rfk, gZ[m]);
        gZ[m] = mfma16(ldW(FB_Whh + ks * 12 + 4 + m), xrk, gZ[m]);
        gN[m] = mfma16(ldW(FB_Wih + ks * 12 + 8 + m), rfk, gN[m]);   // in_
        gH[m] = mfma16(ldW(FB_Whh + ks * 12 + 8 + m), xrk, gH[m]);   // hn
      }
    }
    float part = 0.f;
#pragma unroll
    for (int m = 0; m < 4; m++)
#pragma unroll
      for (int r = 0; r < 4; r++) {
        float rr = sigmoidf_(gR[m][r]);
        float zz = sigmoidf_(gZ[m][r]);
        float nval = tanhf_(gN[m][r] + rr * gH[m][r]);
        float hnx = (1.f - zz) * nval + zz * htv[m][r];
        part += hnx * wpv[m][r];
      }
    part += __shfl_xor(part, 16, 64);
    part += __shfl_xor(part, 32, 64);
    if (lane < 16) out[t0 + tbase + lane] = sigmoidf_(part + bpv);
  };
  gruStream(nfA, xrA, gtA, 0);
  gruStream(nfB, xrB, gtB, 16);
}

// ---------------- launcher ----------------
extern "C" void kernel_launch(void* const* d_in, const int* in_sizes, int n_in,
                              void* d_out, int out_size, void* d_ws, size_t ws_size,
                              hipStream_t stream) {
  const int*   qt     = (const int*)d_in[1];
  const float* ht     = (const float*)d_in[2];
  const float* onehot = (const float*)d_in[3];
  const float* kc     = (const float*)d_in[4];
  const float* graphs = (const float*)d_in[5];
  const float* nw     = (const float*)d_in[6];
  const float* Ws1    = (const float*)d_in[7];
  const float* bs1    = (const float*)d_in[8];
  const float* Ws2    = (const float*)d_in[9];
  const float* bs2    = (const float*)d_in[10];
  const float* Wn1    = (const float*)d_in[11];
  const float* bn1    = (const float*)d_in[12];
  const float* Wn2    = (const float*)d_in[13];
  const float* bn2    = (const float*)d_in[14];
  const float* eaw    = (const float*)d_in[15];
  const float* We     = (const float*)d_in[16];
  const float* be     = (const float*)d_in[17];
  const float* Wa     = (const float*)d_in[18];
  const float* ba     = (const float*)d_in[19];
  const float* Wih    = (const float*)d_in[20];
  const float* bih    = (const float*)d_in[21];
  const float* Whh    = (const float*)d_in[22];
  const float* bhh    = (const float*)d_in[23];
  const float* Wp     = (const float*)d_in[24];
  const float* bp     = (const float*)d_in[25];
  float* out = (float*)d_out;

  float* adjw    = (float*)((char*)d_ws + kAdjOff);
  float* biasTab = (float*)((char*)d_ws + kBiasOff);
  uint4* wfragU  = (uint4*)((char*)d_ws + kFragOff);

  prep_adj_kernel<<<8, 256, 0, stream>>>(qt, onehot, graphs, adjw);
  prep_bias_kernel<<<768, 256, 0, stream>>>(kc, Wn1, bn1, Ws1, bs1, biasTab);
  prep_wfrag_kernel<<<112, 64, 0, stream>>>(Wn1, Wn2, Ws1, Ws2, We, Wa, Wih, Whh, wfragU);
  gkt_main_kernel<<<2048, 256, 0, stream>>>(qt, onehot, ht, nw, bn2, be, ba, bih, bhh,
                                            Wp, bp, eaw, bs2, adjw, biasTab,
                                            (const bf16x8*)wfragU, out);
}

// Round 12
// 259.751 us; speedup vs baseline: 1.0793x; 1.0793x over previous
//
#include <hip/hip_runtime.h>

#define DEVINL __device__ __forceinline__

typedef __bf16 bf16x8 __attribute__((ext_vector_type(8)));
typedef float  f32x4  __attribute__((ext_vector_type(4)));

// ---------------- constants / ws layout ----------------
// B=256, C=1024, H=64, E=64, K=2, MI=128, tokens T = 262144
static constexpr size_t kAdjOff  = 0;                 // 2*1024 f32 (8 KB)
static constexpr size_t kBiasOff = 8192;              // 64*3*4*64*4 f32 = 786432 B
static constexpr size_t kFragOff = 8192 + 786432;     // 112 frags * 1024 B = 114688 B

// Weight fragments (units: one frag = 64 lanes * 16 B).
// Built by prep_wfrag as B-frags of W: lane l slot j = W[32ks+pi(q,j)][16nt+(l&15)].
// Used since r19 as the A-frag of W^T (m-tile = nt) -- same bytes, no prep change.
static constexpr int FB_Wn1h0 = 0,  FB_Wn1h1 = 8,  FB_Wn2_0 = 16, FB_Wn2_1 = 24;
static constexpr int FB_Ws1h  = 32, FB_Ws2   = 40, FB_We    = 48, FB_Wa    = 56;
static constexpr int FB_Wih   = 64, FB_Whh   = 88;

// ---------------- helpers ----------------
DEVINL unsigned short bf16r(float f) {           // RTNE float->bf16
  unsigned u = __builtin_bit_cast(unsigned, f);
  unsigned r = ((u >> 16) & 1u) + 0x7FFFu;
  return (unsigned short)((u + r) >> 16);
}
DEVINL float sigmoidf_(float x) { return __builtin_amdgcn_rcpf(1.f + __expf(-x)); }
DEVINL float tanhf_(float x)    { return 1.f - 2.f * __builtin_amdgcn_rcpf(1.f + __expf(2.f * x)); }

// HW packed f32->bf16 (RNE)
DEVINL unsigned pkbf(float a, float b) {
  unsigned d;
  asm("v_cvt_pk_bf16_f32 %0, %1, %2" : "=v"(d) : "v"(a), "v"(b));
  return d;
}

DEVINL f32x4 mfma16(bf16x8 a, bf16x8 b, f32x4 c) {
  return __builtin_amdgcn_mfma_f32_16x16x32_bf16(a, b, c, 0, 0, 0);
}

DEVINL unsigned clip2_(unsigned x) {   // clamp two packed bf16 to [-5,5]; exact repack
  float lo = __builtin_bit_cast(float, x << 16);
  float hi = __builtin_bit_cast(float, x & 0xFFFF0000u);
  lo = fminf(fmaxf(lo, -5.f), 5.f);
  hi = fminf(fmaxf(hi, -5.f), 5.f);
  return (__builtin_bit_cast(unsigned, lo) >> 16) | (__builtin_bit_cast(unsigned, hi) & 0xFFFF0000u);
}
DEVINL bf16x8 clip5(bf16x8 a) {
  uint4 u = __builtin_bit_cast(uint4, a);
  u.x = clip2_(u.x); u.y = clip2_(u.y); u.z = clip2_(u.z); u.w = clip2_(u.w);
  return __builtin_bit_cast(bf16x8, u);
}

// D-regs -> B-frag (the swapped-operand register handoff).
// B-frag slot j (phys k = ks*32 + pi(q,j)): j<4 <- m-tile 2ks reg r=j (h=32ks+q*4+j);
// j>=4 <- m-tile 2ks+1 reg r=j-4 (h=32ks+16+q*4+(j-4)). Pure VALU: 4 cvt_pk.
DEVINL bf16x8 d2b(f32x4 lo, f32x4 hi) {
  uint4 t;
  t.x = pkbf(lo[0], lo[1]);
  t.y = pkbf(lo[2], lo[3]);
  t.z = pkbf(hi[0], hi[1]);
  t.w = pkbf(hi[2], hi[3]);
  return __builtin_bit_cast(bf16x8, t);
}

// ---------------- prep 1: adjacency vector (SPARSE: a0 has ~5 nonzeros) ----------------
__global__ void prep_adj_kernel(const int* __restrict__ qt, const float* __restrict__ onehot,
                                const float* __restrict__ graphs, float* __restrict__ adjw) {
  __shared__ float a0v[1024];
  __shared__ int   aidx[1024];
  __shared__ int   s_nnz;
  __shared__ float s_den;
  const int tid = threadIdx.x;
  const int k = blockIdx.x >> 2, chunk = blockIdx.x & 3;   // 8 blocks: 2k x 4 chunks of 256 d
  if (tid == 0) { s_nnz = 0; s_den = 0.f; }
  __syncthreads();
  const int q0 = qt[0];
  float lsum = 0.f;
#pragma unroll
  for (int i = 0; i < 4; i++) {
    int c = tid * 4 + i;
    float v = onehot[(size_t)q0 * 1024 + c];
    lsum += v;
    if (v != 0.f) { int p = atomicAdd(&s_nnz, 1); aidx[p] = c; a0v[p] = v; }
  }
#pragma unroll
  for (int off = 32; off >= 1; off >>= 1) lsum += __shfl_xor(lsum, off, 64);
  if ((tid & 63) == 0) atomicAdd(&s_den, lsum);
  __syncthreads();
  const float denom = fmaxf(s_den, 1.f);
  const int nnz = s_nnz;
  const int d = chunk * 256 + tid;
  const float* G = graphs + (size_t)k * 1048576 + d;
  float sum = 0.f;
  for (int j = 0; j < nnz; j++) sum += a0v[j] * G[(size_t)aidx[j] * 1024];
  adjw[k * 1024 + d] = fminf(fmaxf(sum / denom, -5.f), 5.f);
}

// ---------------- prep 2: per-c bias tables (kc folded into layer-1 bias) ----------------
// Transposed-D layout (r19): element (h, t) of block c16:
// biasTab[(((c16*3+tab)*4 + (h>>4))*64 + ((h&15)>>2)*16 + (c&15))*4 + (h&3)]
__global__ void prep_bias_kernel(const float* __restrict__ kc, const float* __restrict__ Wn1,
                                 const float* __restrict__ bn1, const float* __restrict__ Ws1,
                                 const float* __restrict__ bs1, float* __restrict__ biasTab) {
  int gid = blockIdx.x * 256 + threadIdx.x;   // 196608 total
  int j = gid & 63;                           // h (output feature)
  int c = (gid >> 6) & 1023;                  // token column
  int tab = gid >> 16;                        // 0,1 neigh-k; 2 self
  const float* kcr = kc + (size_t)c * 64;
  float s;
  if (tab < 2) {
    s = bn1[tab * 64 + j];
    const float* W = Wn1 + ((size_t)tab * 256 + 192) * 64 + j;   // kc rows of neigh net
#pragma unroll 4
    for (int e = 0; e < 64; e++) s += fminf(fmaxf(kcr[e], -5.f), 5.f) * W[(size_t)e * 64];
  } else {
    s = bs1[j];
    const float* W = Ws1 + (size_t)64 * 64 + j;                  // kc rows of self net (unclipped)
#pragma unroll 4
    for (int e = 0; e < 64; e++) s += kcr[e] * W[(size_t)e * 64];
  }
  int c16 = c >> 4, m = j >> 4, qh = (j & 15) >> 2, r = j & 3, tc = c & 15;
  biasTab[(size_t)((((c16 * 3 + tab) * 4 + m) * 64 + qh * 16 + tc)) * 4 + r] = s;
}

// ---------------- prep 3: weights -> bf16 fragments (pi-permuted; UNCHANGED) ------------
__global__ void prep_wfrag_kernel(const float* __restrict__ Wn1, const float* __restrict__ Wn2,
                                  const float* __restrict__ Ws1, const float* __restrict__ Ws2,
                                  const float* __restrict__ We,  const float* __restrict__ Wa,
                                  const float* __restrict__ Wih, const float* __restrict__ Whh,
                                  uint4* __restrict__ wfrag) {
  const int bid = blockIdx.x, lane = threadIdx.x;   // 112 blocks x 64 threads
  int mat, ks, nt;
  if (bid < 64) { mat = bid >> 3; ks = (bid >> 2) & 1; nt = bid & 3; }
  else { int f2 = bid - 64; mat = 8 + f2 / 24; int f = f2 % 24; ks = f / 12; nt = f % 12; }
  const float* base = Wn1; int stride = 64;
  switch (mat) {
    case 0: base = Wn1 + (size_t)128 * 64; break;          // Wn1 k0, ht rows 128..191
    case 1: base = Wn1 + (size_t)(256 + 128) * 64; break;  // Wn1 k1
    case 2: base = Wn2; break;
    case 3: base = Wn2 + (size_t)64 * 64; break;
    case 4: base = Ws1; break;                             // rows 0..63 (ht part)
    case 5: base = Ws2; break;
    case 6: base = We; break;
    case 7: base = Wa; break;
    case 8: base = Wih; stride = 192; break;
    case 9: base = Whh; stride = 192; break;
  }
  const int qq = lane >> 4, col = nt * 16 + (lane & 15);
  union { unsigned short u[8]; uint4 v; } tmp;
#pragma unroll
  for (int jj = 0; jj < 8; jj++) {
    int k = ks * 32 + ((jj < 4) ? (qq * 4 + jj) : (16 + qq * 4 + (jj - 4)));
    tmp.u[jj] = bf16r(base[(size_t)k * stride + col]);
  }
  wfrag[(size_t)bid * 64 + lane] = tmp.v;
}

// ---------------- main fused kernel ----------------
// ROUND 20: r19 swapped-operand register pipeline (zero activation-LDS, zero
// volatile asm, all layer handoffs = 4x cvt_pk) + r17's GRU-frag LDS staging
// restored. r19 post-mortem: the 102us regression came from the GRU block's 48
// UNPREFETCHED inline L2 frag loads (r17 had them as 120cy block-shared LDS reads)
// plus a 5MB spill from their address pressure. Fix: stage all 48 GRU frags in
// 48KB __shared__ once per block (12 coalesced loads/wave), read-only after one
// __syncthreads -- plain C++ LDS loads, freely schedulable, conflict-free b128.
// LDS 48KB x 2 blocks/CU = 96KB. Everything else byte-identical to r19.
__global__ __launch_bounds__(256, 2) void gkt_main_kernel(
    const int* __restrict__ qt, const float* __restrict__ onehot, const float* __restrict__ ht,
    const float* __restrict__ nw, const float* __restrict__ bn2, const float* __restrict__ be,
    const float* __restrict__ ba, const float* __restrict__ bih, const float* __restrict__ bhh,
    const float* __restrict__ Wp, const float* __restrict__ bp, const float* __restrict__ eaw,
    const float* __restrict__ bs2, const float* __restrict__ adjw, const float* __restrict__ biasTab,
    const bf16x8* __restrict__ wfrag, float* __restrict__ out) {
  __shared__ __align__(16) uint4 gfrag[48 * 64];   // Wih(0..23), Whh(24..47)

  const int tid = threadIdx.x;
  const int wv = tid >> 6, lane = tid & 63;
  const int q = lane >> 4, tl = lane & 15;
  const int t0 = (blockIdx.x * 4 + wv) * 32;
  const int b = t0 >> 10, c0 = t0 & 1023, c16 = c0 >> 4;
  const int cA = c0 + tl, cB = cA + 16;
  const size_t gtA = (size_t)t0 + tl, gtB = gtA + 16;

  // ---- cooperative: 48 GRU frags -> LDS (12 per wave, once per block) ----
  {
    const uint4* wf4 = (const uint4*)wfrag;
#pragma unroll
    for (int i = 0; i < 12; i++) {
      int f = wv * 12 + i;
      gfrag[f * 64 + lane] = wf4[(64 + f) * 64 + lane];   // FB_Wih..FB_Whh+23 == 64+f
    }
  }

  // ---- per-token scalars (token = lane&15; broadcast across q-groups) ----
  const int qb = qt[b];
  const float mkA = onehot[(size_t)qb * 1024 + cA];
  const float mkB = onehot[(size_t)qb * 1024 + cB];
  const float adA0 = adjw[cA], adA1 = adjw[1024 + cA];
  const float adB0 = adjw[cB], adB1 = adjw[1024 + cB];
  const float gA = eaw[cA], gB = eaw[cB];
  const float wmix = fminf(fmaxf(nw[0], 0.1f), 0.9f);

  // ---- ht as B-frags: frag ks, slot j = ht[c][32ks + pi(q,j)] ----
  const float4* ht4 = (const float4*)ht;
  auto loadHtB = [&](size_t gt, int ks) -> bf16x8 {
    float4 v0 = ht4[gt * 16 + 8 * ks + q];        // feats 32ks+q*4 .. +3   (j=0..3)
    float4 v1 = ht4[gt * 16 + 8 * ks + 4 + q];    // feats 32ks+16+q*4 .. +3 (j=4..7)
    uint4 t;
    t.x = pkbf(v0.x, v0.y); t.y = pkbf(v0.z, v0.w);
    t.z = pkbf(v1.x, v1.y); t.w = pkbf(v1.z, v1.w);
    return __builtin_bit_cast(bf16x8, t);
  };
  bf16x8 xrA[2] = {loadHtB(gtA, 0), loadHtB(gtA, 1)};
  bf16x8 xrB[2] = {loadHtB(gtB, 0), loadHtB(gtB, 1)};

  auto ldW = [&](int frag) -> bf16x8 { return wfrag[frag * 64 + lane]; };  // L2 A-operand
  auto ldG = [&](int fr) -> bf16x8 {                                      // LDS A-operand
    return *(const bf16x8*)&gfrag[fr * 64 + lane];
  };
  const f32x4* bt4 = (const f32x4*)biasTab;

  f32x4 nfA[4], nfB[4];   // nf[m][r]: feature h = 16m + q*4 + r, token = lane&15

  // ---- weight prefetch (one phase ahead; source-order, r15-proven) ----
  bf16x8 fX[8], fY[8];
#pragma unroll
  for (int i = 0; i < 8; i++) fX[i] = ldW(FB_Wn1h0 + i);   // fX[ks*4+m]

  __syncthreads();   // gfrag staging visible (read-only afterwards)

  // ---- neighbor path ----
#pragma unroll
  for (int k2 = 0; k2 < 2; k2++) {
#pragma unroll
    for (int i = 0; i < 8; i++) fY[i] = ldW((k2 ? FB_Wn2_1 : FB_Wn2_0) + i);
    bf16x8 xcA[2] = {clip5(xrA[0]), clip5(xrA[1])};
    bf16x8 xcB[2] = {clip5(xrB[0]), clip5(xrB[1])};
    f32x4 acA[4], acB[4];
#pragma unroll
    for (int m = 0; m < 4; m++) {
      acA[m] = bt4[(((c16    ) * 3 + k2) * 4 + m) * 64 + lane];
      acB[m] = bt4[(((c16 + 1) * 3 + k2) * 4 + m) * 64 + lane];
    }
#pragma unroll
    for (int ks = 0; ks < 2; ks++)
#pragma unroll
      for (int m = 0; m < 4; m++) {
        bf16x8 w = fX[ks * 4 + m];
        acA[m] = mfma16(w, xcA[ks], acA[m]);
        acB[m] = mfma16(w, xcB[ks], acB[m]);
      }
    // prefetch next phase's layer-1 frags
#pragma unroll
    for (int i = 0; i < 8; i++) fX[i] = ldW((k2 ? FB_Ws1h : FB_Wn1h1) + i);
    // relu -> register handoff to layer 2
    f32x4 r1A[4], r1B[4];
#pragma unroll
    for (int m = 0; m < 4; m++)
#pragma unroll
      for (int r = 0; r < 4; r++) {
        r1A[m][r] = fmaxf(acA[m][r], 0.f);
        r1B[m][r] = fmaxf(acB[m][r], 0.f);
      }
    bf16x8 pA0 = d2b(r1A[0], r1A[1]), pA1 = d2b(r1A[2], r1A[3]);
    bf16x8 pB0 = d2b(r1B[0], r1B[1]), pB1 = d2b(r1B[2], r1B[3]);
    f32x4 c2A[4], c2B[4];
#pragma unroll
    for (int m = 0; m < 4; m++) {
      f32x4 bz = *(const f32x4*)&bn2[k2 * 64 + m * 16 + q * 4];
      c2A[m] = bz; c2B[m] = bz;
    }
#pragma unroll
    for (int m = 0; m < 4; m++) {
      c2A[m] = mfma16(fY[m],     pA0, c2A[m]);
      c2A[m] = mfma16(fY[4 + m], pA1, c2A[m]);
      c2B[m] = mfma16(fY[m],     pB0, c2B[m]);
      c2B[m] = mfma16(fY[4 + m], pB1, c2B[m]);
    }
#pragma unroll
    for (int m = 0; m < 4; m++)
#pragma unroll
      for (int r = 0; r < 4; r++) {
        float nbA = fminf(fmaxf(c2A[m][r], 0.f), 5.f);
        float nbB = fminf(fmaxf(c2B[m][r], 0.f), 5.f);
        float vA = (k2 ? adA1 : adA0) * nbA;
        float vB = (k2 ? adB1 : adB0) * nbB;
        if (k2 == 0) {
          nfA[m][r] = wmix * fminf(fmaxf(vA, -5.f), 5.f);
          nfB[m][r] = wmix * fminf(fmaxf(vB, -5.f), 5.f);
        } else {
          nfA[m][r] = fminf(fmaxf(nfA[m][r] + (1.f - wmix) * vA, -5.f), 5.f);
          nfB[m][r] = fminf(fmaxf(nfB[m][r] + (1.f - wmix) * vB, -5.f), 5.f);
        }
      }
  }

  // ---- self path (fX holds Ws1h) ----
  bool anySelf = __any((mkA > 0.5f) || (mkB > 0.5f));
  if (anySelf) {
#pragma unroll
    for (int i = 0; i < 8; i++) fY[i] = ldW(FB_Ws2 + i);
    f32x4 acA[4], acB[4];
#pragma unroll
    for (int m = 0; m < 4; m++) {
      acA[m] = bt4[(((c16    ) * 3 + 2) * 4 + m) * 64 + lane];
      acB[m] = bt4[(((c16 + 1) * 3 + 2) * 4 + m) * 64 + lane];
    }
#pragma unroll
    for (int ks = 0; ks < 2; ks++)
#pragma unroll
      for (int m = 0; m < 4; m++) {
        bf16x8 w = fX[ks * 4 + m];
        acA[m] = mfma16(w, xrA[ks], acA[m]);    // raw (unclipped) ht
        acB[m] = mfma16(w, xrB[ks], acB[m]);
      }
    f32x4 r1A[4], r1B[4];
#pragma unroll
    for (int m = 0; m < 4; m++)
#pragma unroll
      for (int r = 0; r < 4; r++) {
        r1A[m][r] = fmaxf(acA[m][r], 0.f);
        r1B[m][r] = fmaxf(acB[m][r], 0.f);
      }
    bf16x8 pA0 = d2b(r1A[0], r1A[1]), pA1 = d2b(r1A[2], r1A[3]);
    bf16x8 pB0 = d2b(r1B[0], r1B[1]), pB1 = d2b(r1B[2], r1B[3]);
    f32x4 c2A[4], c2B[4];
#pragma unroll
    for (int m = 0; m < 4; m++) {
      f32x4 bz = *(const f32x4*)&bs2[m * 16 + q * 4];
      c2A[m] = bz; c2B[m] = bz;
    }
#pragma unroll
    for (int m = 0; m < 4; m++) {
      c2A[m] = mfma16(fY[m],     pA0, c2A[m]);
      c2A[m] = mfma16(fY[4 + m], pA1, c2A[m]);
      c2B[m] = mfma16(fY[m],     pB0, c2B[m]);
      c2B[m] = mfma16(fY[4 + m], pB1, c2B[m]);
    }
#pragma unroll
    for (int m = 0; m < 4; m++)
#pragma unroll
      for (int r = 0; r < 4; r++) {
        float sfA = fminf(fmaxf(c2A[m][r], 0.f), 10.f);
        float sfB = fminf(fmaxf(c2B[m][r], 0.f), 10.f);
        nfA[m][r] = (mkA > 0.5f) ? sfA : nfA[m][r];
        nfB[m][r] = (mkB > 0.5f) ? sfB : nfB[m][r];
      }
  }

  // ---- res = m - g*sigmoid(m@We+be)*m + g*tanh(m@Wa+ba) ----
#pragma unroll
  for (int i = 0; i < 8; i++) fX[i] = ldW(FB_We + i);
  bf16x8 mA0 = d2b(nfA[0], nfA[1]), mA1 = d2b(nfA[2], nfA[3]);
  bf16x8 mB0 = d2b(nfB[0], nfB[1]), mB1 = d2b(nfB[2], nfB[3]);
  {
#pragma unroll
    for (int i = 0; i < 8; i++) fY[i] = ldW(FB_Wa + i);
    f32x4 eA[4], eB[4];
#pragma unroll
    for (int m = 0; m < 4; m++) {
      f32x4 bz = *(const f32x4*)&be[m * 16 + q * 4];
      eA[m] = bz; eB[m] = bz;
    }
#pragma unroll
    for (int m = 0; m < 4; m++) {
      eA[m] = mfma16(fX[m],     mA0, eA[m]);
      eA[m] = mfma16(fX[4 + m], mA1, eA[m]);
      eB[m] = mfma16(fX[m],     mB0, eB[m]);
      eB[m] = mfma16(fX[4 + m], mB1, eB[m]);
    }
#pragma unroll
    for (int m = 0; m < 4; m++)
#pragma unroll
      for (int r = 0; r < 4; r++) {
        float mAv = nfA[m][r], mBv = nfB[m][r];
        nfA[m][r] = mAv - gA * sigmoidf_(eA[m][r]) * mAv;
        nfB[m][r] = mBv - gB * sigmoidf_(eB[m][r]) * mBv;
      }
    f32x4 aA[4], aB[4];
#pragma unroll
    for (int m = 0; m < 4; m++) {
      f32x4 bz = *(const f32x4*)&ba[m * 16 + q * 4];
      aA[m] = bz; aB[m] = bz;
    }
#pragma unroll
    for (int m = 0; m < 4; m++) {
      aA[m] = mfma16(fY[m],     mA0, aA[m]);
      aA[m] = mfma16(fY[4 + m], mA1, aA[m]);
      aB[m] = mfma16(fY[m],     mB0, aB[m]);
      aB[m] = mfma16(fY[4 + m], mB1, aB[m]);
    }
#pragma unroll
    for (int m = 0; m < 4; m++)
#pragma unroll
      for (int r = 0; r < 4; r++) {
        nfA[m][r] += gA * tanhf_(aA[m][r]);
        nfB[m][r] += gB * tanhf_(aB[m][r]);
      }
  }

  // ---- GRU gates + output (stream-split; frags from LDS, handoffs in registers) ----
  const float bpv = bp[0];
  auto gruStream = [&](const f32x4* nf, const bf16x8* xr, size_t gt, int tbase) {
    bf16x8 rf0 = d2b(nf[0], nf[1]), rf1 = d2b(nf[2], nf[3]);   // res B-frags
    // epilogue prefetch: fp32 ht + per-feature vectors (short live range)
    f32x4 htv[4], wpv[4], brz[4], bzz[4], bnn[4], bhn[4];
#pragma unroll
    for (int m = 0; m < 4; m++) {
      htv[m] = *(const f32x4*)&ht[gt * 64 + m * 16 + q * 4];
      wpv[m] = *(const f32x4*)&Wp[m * 16 + q * 4];
      f32x4 bi0 = *(const f32x4*)&bih[m * 16 + q * 4];
      f32x4 bh0 = *(const f32x4*)&bhh[m * 16 + q * 4];
      f32x4 bi1 = *(const f32x4*)&bih[64 + m * 16 + q * 4];
      f32x4 bh1 = *(const f32x4*)&bhh[64 + m * 16 + q * 4];
#pragma unroll
      for (int r = 0; r < 4; r++) {
        brz[m][r] = bi0[r] + bh0[r];
        bzz[m][r] = bi1[r] + bh1[r];
      }
      bnn[m] = *(const f32x4*)&bih[128 + m * 16 + q * 4];
      bhn[m] = *(const f32x4*)&bhh[128 + m * 16 + q * 4];
    }
    f32x4 gR[4], gZ[4], gN[4], gH[4];
#pragma unroll
    for (int m = 0; m < 4; m++) { gR[m] = brz[m]; gZ[m] = bzz[m]; gN[m] = bnn[m]; gH[m] = bhn[m]; }
#pragma unroll
    for (int ks = 0; ks < 2; ks++) {
      bf16x8 rfk = ks ? rf1 : rf0;
      bf16x8 xrk = xr[ks];
#pragma unroll
      for (int m = 0; m < 4; m++) {
        gR[m] = mfma16(ldG(ks * 12 + m),          rfk, gR[m]);   // Wih_r
        gR[m] = mfma16(ldG(24 + ks * 12 + m),     xrk, gR[m]);   // Whh_r
        gZ[m] = mfma16(ldG(ks * 12 + 4 + m),      rfk, gZ[m]);   // Wih_z
        gZ[m] = mfma16(ldG(24 + ks * 12 + 4 + m), xrk, gZ[m]);   // Whh_z
        gN[m] = mfma16(ldG(ks * 12 + 8 + m),      rfk, gN[m]);   // Wih_n (in_)
        gH[m] = mfma16(ldG(24 + ks * 12 + 8 + m), xrk, gH[m]);   // Whh_n (hn)
      }
    }
    float part = 0.f;
#pragma unroll
    for (int m = 0; m < 4; m++)
#pragma unroll
      for (int r = 0; r < 4; r++) {
        float rr = sigmoidf_(gR[m][r]);
        float zz = sigmoidf_(gZ[m][r]);
        float nval = tanhf_(gN[m][r] + rr * gH[m][r]);
        float hnx = (1.f - zz) * nval + zz * htv[m][r];
        part += hnx * wpv[m][r];
      }
    part += __shfl_xor(part, 16, 64);
    part += __shfl_xor(part, 32, 64);
    if (lane < 16) out[t0 + tbase + lane] = sigmoidf_(part + bpv);
  };
  gruStream(nfA, xrA, gtA, 0);
  gruStream(nfB, xrB, gtB, 16);
}

// ---------------- launcher ----------------
extern "C" void kernel_launch(void* const* d_in, const int* in_sizes, int n_in,
                              void* d_out, int out_size, void* d_ws, size_t ws_size,
                              hipStream_t stream) {
  const int*   qt     = (const int*)d_in[1];
  const float* ht     = (const float*)d_in[2];
  const float* onehot = (const float*)d_in[3];
  const float* kc     = (const float*)d_in[4];
  const float* graphs = (const float*)d_in[5];
  const float* nw     = (const float*)d_in[6];
  const float* Ws1    = (const float*)d_in[7];
  const float* bs1    = (const float*)d_in[8];
  const float* Ws2    = (const float*)d_in[9];
  const float* bs2    = (const float*)d_in[10];
  const float* Wn1    = (const float*)d_in[11];
  const float* bn1    = (const float*)d_in[12];
  const float* Wn2    = (const float*)d_in[13];
  const float* bn2    = (const float*)d_in[14];
  const float* eaw    = (const float*)d_in[15];
  const float* We     = (const float*)d_in[16];
  const float* be     = (const float*)d_in[17];
  const float* Wa     = (const float*)d_in[18];
  const float* ba     = (const float*)d_in[19];
  const float* Wih    = (const float*)d_in[20];
  const float* bih    = (const float*)d_in[21];
  const float* Whh    = (const float*)d_in[22];
  const float* bhh    = (const float*)d_in[23];
  const float* Wp     = (const float*)d_in[24];
  const float* bp     = (const float*)d_in[25];
  float* out = (float*)d_out;

  float* adjw    = (float*)((char*)d_ws + kAdjOff);
  float* biasTab = (float*)((char*)d_ws + kBiasOff);
  uint4* wfragU  = (uint4*)((char*)d_ws + kFragOff);

  prep_adj_kernel<<<8, 256, 0, stream>>>(qt, onehot, graphs, adjw);
  prep_bias_kernel<<<768, 256, 0, stream>>>(kc, Wn1, bn1, Ws1, bs1, biasTab);
  prep_wfrag_kernel<<<112, 64, 0, stream>>>(Wn1, Wn2, Ws1, Ws2, We, Wa, Wih, Whh, wfragU);
  gkt_main_kernel<<<2048, 256, 0, stream>>>(qt, onehot, ht, nw, bn2, be, ba, bih, bhh,
                                            Wp, bp, eaw, bs2, adjw, biasTab,
                                            (const bf16x8*)wfragU, out);
}